// Round 19
// baseline (104.713 us; speedup 1.0000x reference)
//
#include <hip/hip_runtime.h>
#include <hip/hip_fp16.h>
#include <cstdint>

#define NT      32768
#define DIN     256
#define DHID    1024
#define DOUT    256
#define NPLANES 8
#define NBLK    (NT / 256)

typedef unsigned short u16;
typedef __attribute__((ext_vector_type(8))) _Float16 f16x8;
typedef __attribute__((ext_vector_type(4))) float    f32x4;

// ---------------- workspace layout (bytes) ----------------
#define WS_OFFSETS 0                           // 9 ints (scatter_k blk 0)
#define WS_META    64                          // 1 int: ntiles (64-gran)
#define WS_TP      1024                        // <=544 ints
#define WS_TM      (WS_TP + 544*4)
#define WS_BLKHIST (WS_TM + 544*4)
#define WS_PERM    (WS_BLKHIST + NBLK*8*4)     // NT ints
#define WS_XB      (WS_PERM + NT*4)            // NT*DIN f16, natural order
#define WS_W1B     (WS_XB + NT*DIN*2)
#define WS_W2B     (WS_W1B + NPLANES*DHID*DIN*2)
#define WS_HB      (WS_W2B + NPLANES*DOUT*DHID*2)   // NT*DHID f16, bucketed

__device__ __forceinline__ u16 f2h_bits(float f) {
    __half h = __float2half(f);
    return *reinterpret_cast<u16*>(&h);
}

__device__ __forceinline__ void gl_lds16(const void* g, void* l) {
    __builtin_amdgcn_global_load_lds(
        (const __attribute__((address_space(1))) void*)g,
        (__attribute__((address_space(3))) void*)l,
        16, 0, 0);
}

// fast gelu: tanh-form, |dev vs exact erf-gelu| <~ 5e-4 (negligible after W2)
__device__ __forceinline__ float gelu_fast(float x) {
    const float u = x * (1.5957691216f + 0.07135481283f * x * x);
    const float e = __expf(-u);
    return x * __builtin_amdgcn_rcpf(1.0f + e);
}

// ---------------- prep: per-block hist + f32->f16 converts ----------
__global__ void prep_k(const int* __restrict__ pidx, const float* __restrict__ x,
                       const float* __restrict__ W1, const float* __restrict__ W2,
                       int* __restrict__ blkhist, u16* __restrict__ xb,
                       u16* __restrict__ w1b, u16* __restrict__ w2b) {
    __shared__ int cnt[NPLANES];
    const int t = threadIdx.x, lane = t & 63;
    if ((int)blockIdx.x < NBLK) {
        if (t < NPLANES) cnt[t] = 0;
        __syncthreads();
        const int p = pidx[blockIdx.x * 256 + t];
#pragma unroll
        for (int q = 0; q < NPLANES; ++q) {
            unsigned long long m = __ballot(p == q);
            if (p == q && __popcll(m & ((1ULL << lane) - 1)) == 0)
                atomicAdd(&cnt[q], __popcll(m));
        }
        __syncthreads();
        if (t < NPLANES) blkhist[blockIdx.x * NPLANES + t] = cnt[t];
    }
    const int n0 = NT * DIN / 4, n1 = NPLANES * DHID * DIN / 4, n2 = NPLANES * DOUT * DHID / 4;
    const int stride = gridDim.x * blockDim.x;
    for (int i = blockIdx.x * blockDim.x + t; i < n0 + n1 + n2; i += stride) {
        const float4* s; ushort4* d; int j;
        if (i < n0)           { s = (const float4*)x;  d = (ushort4*)xb;  j = i; }
        else if (i < n0 + n1) { s = (const float4*)W1; d = (ushort4*)w1b; j = i - n0; }
        else                  { s = (const float4*)W2; d = (ushort4*)w2b; j = i - n0 - n1; }
        float4 v = s[j];
        ushort4 o;
        o.x = f2h_bits(v.x); o.y = f2h_bits(v.y);
        o.z = f2h_bits(v.z); o.w = f2h_bits(v.w);
        d[j] = o;
    }
}

// ---------------- scatter + inline scan + parallel tile-list build ------------
__global__ void scatter_k(const int* __restrict__ pidx, const int* __restrict__ blkhist,
                          int* __restrict__ offsets, int* __restrict__ meta,
                          int* __restrict__ tp, int* __restrict__ tm,
                          int* __restrict__ perm) {
    __shared__ int stot[NPLANES], spre[NPLANES], sbase[NPLANES];
    __shared__ int wcnt[4][NPLANES], wbase[4][NPLANES];
    const int t = threadIdx.x, lane = t & 63, wave = t >> 6;
    if (t < NPLANES) {
        int tot = 0, pre = 0;
        for (int b = 0; b < NBLK; ++b) {
            const int v = blkhist[b * NPLANES + t];
            tot += v;
            if (b < (int)blockIdx.x) pre += v;
        }
        stot[t] = tot; spre[t] = pre;
    }
    __syncthreads();
    if (t == 0) {
        int run = 0;
        for (int q = 0; q < NPLANES; ++q) {
            sbase[q] = run + spre[q];
            if (blockIdx.x == 0) offsets[q] = run;
            run += stot[q];
        }
        if (blockIdx.x == 0) offsets[NPLANES] = run;
    }
    __syncthreads();
    if (blockIdx.x == 0 && t < NPLANES) {
        int pre = 0, ntiles = 0;
#pragma unroll
        for (int q = 0; q < NPLANES; ++q) {
            const int ntq = (stot[q] + 63) >> 6;
            if (q < t) pre += ntq;
            ntiles += ntq;
        }
        for (int m = 0, i = pre; m < stot[t]; m += 64, ++i) { tp[i] = t; tm[i] = m; }
        if (t == 0) meta[0] = ntiles;
    }
    const int i = blockIdx.x * 256 + t;
    const int p = pidx[i];
    int rank = 0;
#pragma unroll
    for (int q = 0; q < NPLANES; ++q) {
        unsigned long long m = __ballot(p == q);
        if (lane == 0) wcnt[wave][q] = __popcll(m);
        if (p == q) rank = __popcll(m & ((1ULL << lane) - 1));
    }
    __syncthreads();
    if (t < NPLANES) {
        int run = sbase[t];
#pragma unroll
        for (int w = 0; w < 4; ++w) { wbase[w][t] = run; run += wcnt[w][t]; }
    }
    __syncthreads();
    perm[wbase[wave][p] + rank] = i;
}

// XCD-chunked tile mapping (VERIFIED R6: XCD = linear_block_id % 8).
#define XCD_MAP(NSPLIT)                                                        \
    const int ntiles = meta[0];                                                \
    const int xcd = blockIdx.x & 7, idx = blockIdx.x >> 3;                     \
    const int q8 = ntiles >> 3, r8 = ntiles & 7;                               \
    const int tn = q8 + (xcd < r8 ? 1 : 0);                                    \
    if (idx >= tn * (NSPLIT)) return;                                          \
    const int tile = (xcd < r8 ? xcd * (q8 + 1)                                \
                               : r8 * (q8 + 1) + (xcd - r8) * q8)              \
                     + idx / (NSPLIT);                                         \
    const int sub = idx % (NSPLIT);                                            \
    const int p   = tp[tile];                                                  \
    const int m0  = tm[tile];                                                  \
    const int off = offsets[p];                                                \
    const int cnt = offsets[p + 1] - off;

// ---------------- gemm1: 64x128 tile, BK=32 dbuf, 24KB, FENCED raw barriers --
// R18 raced: bare s_barrier has no compiler memory ordering, LDS reads hoisted
// above it. Fix (guide rule #18 / m152): sched_barrier(0) pins on both sides of
// every raw s_barrier + after each inline-asm waitcnt. Counted vmcnt(3): own
// prev-stage loads retired, next-stage 3 stay in flight across the barrier.
__global__ __launch_bounds__(256, 6) void gemm1_k(
    const u16* __restrict__ xb, const u16* __restrict__ w1b,
    const float* __restrict__ b1, const int* __restrict__ perm,
    const int* __restrict__ offsets, const int* __restrict__ meta,
    const int* __restrict__ tp, const int* __restrict__ tm,
    u16* __restrict__ hb)
{
    __shared__ __align__(16) u16 smem[12288];   // buf0 @0, buf1 @6144; sOut reuse
    XCD_MAP(8)
    const int n0v = sub * 128;

    const int tid = threadIdx.x;
    // A: 64 rows x 32K = 4KB = 256 slots (4/row), 1/thread
    const int arow = tid >> 2, ach = tid & 3;
    const u16* aptr = xb + (size_t)perm[off + min(m0 + arow, cnt - 1)] * DIN
                         + ((ach ^ ((arow >> 1) & 3)) * 8);
    // B: 128 rows x 32K = 8KB = 512 slots, 2/thread
    const u16* bptr[2];
#pragma unroll
    for (int c = 0; c < 2; ++c) {
        const int slot = c * 256 + tid, row = slot >> 2, ch = slot & 3;
        bptr[c] = w1b + ((size_t)p * DHID + n0v + row) * DIN
                      + ((ch ^ ((row >> 1) & 3)) * 8);
    }
    const int wave = tid >> 6, lane = tid & 63;
    const int wr = wave >> 1, wc = wave & 1;    // 2x2 waves, wave tile 32x64
    const int lm = lane & 15, lk = lane >> 4;

    f32x4 acc[2][4];
#pragma unroll
    for (int a = 0; a < 2; ++a)
#pragma unroll
        for (int b = 0; b < 4; ++b) acc[a][b] = (f32x4){0.f, 0.f, 0.f, 0.f};

#define STAGE1(buf, kt) do {                                                   \
        gl_lds16(aptr + (kt) * 32, (buf) + tid * 8);                           \
        gl_lds16(bptr[0] + (kt) * 32, (buf) + 2048 + tid * 8);                 \
        gl_lds16(bptr[1] + (kt) * 32, (buf) + 4096 + tid * 8); } while (0)

#define COMPUTE1(buf) do {                                                     \
        f16x8 af[2], bf[4];                                                    \
        _Pragma("unroll") for (int mf = 0; mf < 2; ++mf) {                     \
            const int row = wr * 32 + mf * 16 + lm;                            \
            af[mf] = *(const f16x8*)((buf) + row * 32 +                        \
                                     ((lk ^ ((row >> 1) & 3)) * 8));           \
        }                                                                      \
        _Pragma("unroll") for (int nf = 0; nf < 4; ++nf) {                     \
            const int row = wc * 64 + nf * 16 + lm;                            \
            bf[nf] = *(const f16x8*)((buf) + 2048 + row * 32 +                 \
                                     ((lk ^ ((row >> 1) & 3)) * 8));           \
        }                                                                      \
        _Pragma("unroll") for (int mf = 0; mf < 2; ++mf)                       \
            _Pragma("unroll") for (int nf = 0; nf < 4; ++nf)                   \
                acc[mf][nf] = __builtin_amdgcn_mfma_f32_16x16x32_f16(          \
                    af[mf], bf[nf], acc[mf][nf], 0, 0, 0); } while (0)

#define FENCED_BARRIER() do {                                                  \
        __builtin_amdgcn_sched_barrier(0);                                     \
        __builtin_amdgcn_s_barrier();                                          \
        __builtin_amdgcn_sched_barrier(0); } while (0)

    u16* const buf0 = smem;
    u16* const buf1 = smem + 6144;

    // prologue: stage step 0, full drain
    STAGE1(buf0, 0);
    asm volatile("s_waitcnt vmcnt(0)" ::: "memory");
    FENCED_BARRIER();

    constexpr int KT = DIN / 32;                // 8 steps
#pragma unroll
    for (int kt = 0; kt < KT; ++kt) {
        u16* const cur = (kt & 1) ? buf1 : buf0;
        u16* const nxt = (kt & 1) ? buf0 : buf1;
        if (kt + 1 < KT) {
            STAGE1(nxt, kt + 1);
            // own prev-stage (3 oldest) loads retired; next-stage 3 in flight
            asm volatile("s_waitcnt vmcnt(3)" ::: "memory");
        } else {
            asm volatile("s_waitcnt vmcnt(0)" ::: "memory");
        }
        FENCED_BARRIER();                       // stage-kt writes visible to all
        COMPUTE1(cur);
        FENCED_BARRIER();                       // readers done before cur re-staged
    }
#undef STAGE1
#undef COMPUTE1
#undef FENCED_BARRIER

    // ---- epilogue: fast gelu -> chunk-swizzled sOut, then coalesced copy-out ----
    u16* const sOut = smem;                     // 64 x 128 u16 = 16KB
#pragma unroll
    for (int nf = 0; nf < 4; ++nf) {
        const int col = wc * 64 + nf * 16 + lm;
        const float bb = b1[p * DHID + n0v + col];
        const int cc = col >> 3, c7 = col & 7;
#pragma unroll
        for (int mf = 0; mf < 2; ++mf) {
#pragma unroll
            for (int j = 0; j < 4; ++j) {
                const int tok = wr * 32 + mf * 16 + lk * 4 + j;
                sOut[tok * 128 + ((cc ^ (tok & 15)) * 8) + c7] =
                    f2h_bits(gelu_fast(acc[mf][nf][j] + bb));
            }
        }
    }
    __syncthreads();
    const int r = tid >> 2, qq = tid & 3;       // 4 threads/row, 64B each
    if (m0 + r < cnt) {
        u16* dst = hb + (size_t)(off + m0 + r) * DHID + n0v;
#pragma unroll
        for (int c = 0; c < 4; ++c) {
            const int l = qq * 4 + c;
            *(int4*)(dst + l * 8) = *(const int4*)(sOut + r * 128 + ((l ^ (r & 15)) * 8));
        }
    }
}

// ---------------- gemm2: R17-exact (BK=64, 24KB, launch_bounds(256,6)) -------
__global__ __launch_bounds__(256, 6) void gemm2_k(
    const u16* __restrict__ hb, const u16* __restrict__ w2b,
    const float* __restrict__ b2, const int* __restrict__ perm,
    const int* __restrict__ offsets, const int* __restrict__ meta,
    const int* __restrict__ tp, const int* __restrict__ tm,
    float* __restrict__ out)
{
    __shared__ __align__(16) u16 smem[12288];   // sA 8KB | sB 16KB
    XCD_MAP(2)
    const int n0v = sub * 128;

    u16* const sA = smem;
    u16* const sB = smem + 4096;

    const int tid = threadIdx.x;
    const u16* aptr[2];
    const u16* bptr[4];
#pragma unroll
    for (int c = 0; c < 2; ++c) {
        const int slot = c * 256 + tid, row = slot >> 3, ch = slot & 7;
        aptr[c] = hb + (size_t)(off + min(m0 + row, cnt - 1)) * DHID + ((ch ^ (row & 7)) * 8);
    }
#pragma unroll
    for (int c = 0; c < 4; ++c) {
        const int slot = c * 256 + tid, row = slot >> 3, ch = slot & 7;
        bptr[c] = w2b + ((size_t)p * DOUT + n0v + row) * DHID + ((ch ^ (row & 7)) * 8);
    }
    const int wave = tid >> 6, lane = tid & 63;
    const int wr = wave >> 1, wc = wave & 1;    // 2x2 waves, wave tile 32x64
    const int lm = lane & 15, lk = lane >> 4;

    f32x4 acc[2][4];
#pragma unroll
    for (int a = 0; a < 2; ++a)
#pragma unroll
        for (int b = 0; b < 4; ++b) acc[a][b] = (f32x4){0.f, 0.f, 0.f, 0.f};

    for (int kt = 0; kt < DHID / 64; ++kt) {    // 16 K-steps
        const int k0 = kt * 64;
#pragma unroll
        for (int c = 0; c < 2; ++c) gl_lds16(aptr[c] + k0, sA + c * 2048 + tid * 8);
#pragma unroll
        for (int c = 0; c < 4; ++c) gl_lds16(bptr[c] + k0, sB + c * 2048 + tid * 8);
        __syncthreads();
#pragma unroll
        for (int kk = 0; kk < 2; ++kk) {
            f16x8 af[2], bf[4];
#pragma unroll
            for (int mf = 0; mf < 2; ++mf) {
                const int row = wr * 32 + mf * 16 + lm;
                const int g   = kk * 4 + lk;
                af[mf] = *(const f16x8*)(sA + row * 64 + ((g ^ (row & 7)) * 8));
            }
#pragma unroll
            for (int nf = 0; nf < 4; ++nf) {
                const int row = wc * 64 + nf * 16 + lm;
                const int g   = kk * 4 + lk;
                bf[nf] = *(const f16x8*)(sB + row * 64 + ((g ^ (row & 7)) * 8));
            }
#pragma unroll
            for (int mf = 0; mf < 2; ++mf)
#pragma unroll
                for (int nf = 0; nf < 4; ++nf)
                    acc[mf][nf] = __builtin_amdgcn_mfma_f32_16x16x32_f16(
                        af[mf], bf[nf], acc[mf][nf], 0, 0, 0);
        }
        __syncthreads();
    }

#pragma unroll
    for (int nf = 0; nf < 4; ++nf) {
        const int col = n0v + wc * 64 + nf * 16 + lm;
        const float bb = b2[p * DOUT + col];
#pragma unroll
        for (int mf = 0; mf < 2; ++mf) {
#pragma unroll
            for (int j = 0; j < 4; ++j) {
                const int tok = wr * 32 + mf * 16 + lk * 4 + j;
                if (m0 + tok < cnt)
                    out[(size_t)perm[off + m0 + tok] * DOUT + col] = acc[mf][nf][j] + bb;
            }
        }
    }
}

// ---------------- launch ----------------
extern "C" void kernel_launch(void* const* d_in, const int* in_sizes, int n_in,
                              void* d_out, int out_size, void* d_ws, size_t ws_size,
                              hipStream_t stream) {
    const float* x    = (const float*)d_in[0];
    const float* W1   = (const float*)d_in[1];
    const float* b1   = (const float*)d_in[2];
    const float* W2   = (const float*)d_in[3];
    const float* b2   = (const float*)d_in[4];
    const int*   pidx = (const int*)d_in[5];
    float*       out  = (float*)d_out;

    char* ws      = (char*)d_ws;
    int* offsets  = (int*)(ws + WS_OFFSETS);
    int* meta     = (int*)(ws + WS_META);
    int* tp       = (int*)(ws + WS_TP);
    int* tm       = (int*)(ws + WS_TM);
    int* blkhist  = (int*)(ws + WS_BLKHIST);
    int* perm     = (int*)(ws + WS_PERM);
    u16* xb       = (u16*)(ws + WS_XB);
    u16* w1b      = (u16*)(ws + WS_W1B);
    u16* w2b      = (u16*)(ws + WS_W2B);
    u16* hb       = (u16*)(ws + WS_HB);

    prep_k<<<2048, 256, 0, stream>>>(pidx, x, W1, W2, blkhist, xb, w1b, w2b);
    scatter_k<<<NBLK, 256, 0, stream>>>(pidx, blkhist, offsets, meta, tp, tm, perm);

    // ntiles <= 519 -> tn <= 66/xcd
    // gemm1: NSPLIT=8 (128-col chunks of DHID) -> 8*66*8 = 4224 slots
    gemm1_k<<<4224, 256, 0, stream>>>(xb, w1b, b1, perm, offsets, meta, tp, tm, hb);
    // gemm2: NSPLIT=2 (128-col chunks of DOUT) -> 8*66*2 = 1056 slots
    gemm2_k<<<1056, 256, 0, stream>>>(hb, w2b, b2, perm, offsets, meta, tp, tm, out);
}

// Round 20
// 102.265 us; speedup vs baseline: 1.0239x; 1.0239x over previous
//
#include <hip/hip_runtime.h>
#include <hip/hip_fp16.h>
#include <cstdint>

#define NT      32768
#define DIN     256
#define DHID    1024
#define DOUT    256
#define NPLANES 8
#define NBLK    (NT / 256)

typedef unsigned short u16;
typedef __attribute__((ext_vector_type(8))) _Float16 f16x8;
typedef __attribute__((ext_vector_type(4))) float    f32x4;

// ---------------- workspace layout (bytes) ----------------
#define WS_OFFSETS 0                           // 9 ints (scatter_k blk 0)
#define WS_META    64                          // 1 int: ntiles (64-gran)
#define WS_TP      1024                        // <=544 ints
#define WS_TM      (WS_TP + 544*4)
#define WS_BLKHIST (WS_TM + 544*4)
#define WS_PERM    (WS_BLKHIST + NBLK*8*4)     // NT ints
#define WS_XB      (WS_PERM + NT*4)            // NT*DIN f16, natural order
#define WS_W1B     (WS_XB + NT*DIN*2)
#define WS_W2B     (WS_W1B + NPLANES*DHID*DIN*2)
#define WS_HB      (WS_W2B + NPLANES*DOUT*DHID*2)   // NT*DHID f16, bucketed

__device__ __forceinline__ u16 f2h_bits(float f) {
    __half h = __float2half(f);
    return *reinterpret_cast<u16*>(&h);
}

__device__ __forceinline__ void gl_lds16(const void* g, void* l) {
    __builtin_amdgcn_global_load_lds(
        (const __attribute__((address_space(1))) void*)g,
        (__attribute__((address_space(3))) void*)l,
        16, 0, 0);
}

// fast gelu: tanh-form, |dev vs exact erf-gelu| <~ 5e-4 (negligible after W2)
__device__ __forceinline__ float gelu_fast(float x) {
    const float u = x * (1.5957691216f + 0.07135481283f * x * x);
    const float e = __expf(-u);
    return x * __builtin_amdgcn_rcpf(1.0f + e);
}

// ---------------- prep: per-block hist + f32->f16 converts ----------
__global__ void prep_k(const int* __restrict__ pidx, const float* __restrict__ x,
                       const float* __restrict__ W1, const float* __restrict__ W2,
                       int* __restrict__ blkhist, u16* __restrict__ xb,
                       u16* __restrict__ w1b, u16* __restrict__ w2b) {
    __shared__ int cnt[NPLANES];
    const int t = threadIdx.x, lane = t & 63;
    if ((int)blockIdx.x < NBLK) {
        if (t < NPLANES) cnt[t] = 0;
        __syncthreads();
        const int p = pidx[blockIdx.x * 256 + t];
#pragma unroll
        for (int q = 0; q < NPLANES; ++q) {
            unsigned long long m = __ballot(p == q);
            if (p == q && __popcll(m & ((1ULL << lane) - 1)) == 0)
                atomicAdd(&cnt[q], __popcll(m));
        }
        __syncthreads();
        if (t < NPLANES) blkhist[blockIdx.x * NPLANES + t] = cnt[t];
    }
    const int n0 = NT * DIN / 4, n1 = NPLANES * DHID * DIN / 4, n2 = NPLANES * DOUT * DHID / 4;
    const int stride = gridDim.x * blockDim.x;
    for (int i = blockIdx.x * blockDim.x + t; i < n0 + n1 + n2; i += stride) {
        const float4* s; ushort4* d; int j;
        if (i < n0)           { s = (const float4*)x;  d = (ushort4*)xb;  j = i; }
        else if (i < n0 + n1) { s = (const float4*)W1; d = (ushort4*)w1b; j = i - n0; }
        else                  { s = (const float4*)W2; d = (ushort4*)w2b; j = i - n0 - n1; }
        float4 v = s[j];
        ushort4 o;
        o.x = f2h_bits(v.x); o.y = f2h_bits(v.y);
        o.z = f2h_bits(v.z); o.w = f2h_bits(v.w);
        d[j] = o;
    }
}

// ---------------- scatter + inline scan + parallel tile-list build ------------
__global__ void scatter_k(const int* __restrict__ pidx, const int* __restrict__ blkhist,
                          int* __restrict__ offsets, int* __restrict__ meta,
                          int* __restrict__ tp, int* __restrict__ tm,
                          int* __restrict__ perm) {
    __shared__ int stot[NPLANES], spre[NPLANES], sbase[NPLANES];
    __shared__ int wcnt[4][NPLANES], wbase[4][NPLANES];
    const int t = threadIdx.x, lane = t & 63, wave = t >> 6;
    if (t < NPLANES) {
        int tot = 0, pre = 0;
        for (int b = 0; b < NBLK; ++b) {
            const int v = blkhist[b * NPLANES + t];
            tot += v;
            if (b < (int)blockIdx.x) pre += v;
        }
        stot[t] = tot; spre[t] = pre;
    }
    __syncthreads();
    if (t == 0) {
        int run = 0;
        for (int q = 0; q < NPLANES; ++q) {
            sbase[q] = run + spre[q];
            if (blockIdx.x == 0) offsets[q] = run;
            run += stot[q];
        }
        if (blockIdx.x == 0) offsets[NPLANES] = run;
    }
    __syncthreads();
    if (blockIdx.x == 0 && t < NPLANES) {
        int pre = 0, ntiles = 0;
#pragma unroll
        for (int q = 0; q < NPLANES; ++q) {
            const int ntq = (stot[q] + 63) >> 6;
            if (q < t) pre += ntq;
            ntiles += ntq;
        }
        for (int m = 0, i = pre; m < stot[t]; m += 64, ++i) { tp[i] = t; tm[i] = m; }
        if (t == 0) meta[0] = ntiles;
    }
    const int i = blockIdx.x * 256 + t;
    const int p = pidx[i];
    int rank = 0;
#pragma unroll
    for (int q = 0; q < NPLANES; ++q) {
        unsigned long long m = __ballot(p == q);
        if (lane == 0) wcnt[wave][q] = __popcll(m);
        if (p == q) rank = __popcll(m & ((1ULL << lane) - 1));
    }
    __syncthreads();
    if (t < NPLANES) {
        int run = sbase[t];
#pragma unroll
        for (int w = 0; w < 4; ++w) { wbase[w][t] = run; run += wcnt[w][t]; }
    }
    __syncthreads();
    perm[wbase[wave][p] + rank] = i;
}

// XCD-chunked tile mapping (VERIFIED R6: XCD = linear_block_id % 8).
// REV=1 iterates tiles in REVERSE within each XCD chunk — gemm2 starts on the
// tail of hb that gemm1 wrote last (still L2-hot at the kernel boundary).
#define XCD_MAP(NSPLIT, REV)                                                   \
    const int ntiles = meta[0];                                                \
    const int xcd = blockIdx.x & 7, idx = blockIdx.x >> 3;                     \
    const int q8 = ntiles >> 3, r8 = ntiles & 7;                               \
    const int tn = q8 + (xcd < r8 ? 1 : 0);                                    \
    if (idx >= tn * (NSPLIT)) return;                                          \
    const int ti_ = idx / (NSPLIT);                                            \
    const int tile = (xcd < r8 ? xcd * (q8 + 1)                                \
                               : r8 * (q8 + 1) + (xcd - r8) * q8)              \
                     + ((REV) ? (tn - 1 - ti_) : ti_);                         \
    const int sub = idx % (NSPLIT);                                            \
    const int p   = tp[tile];                                                  \
    const int m0  = tm[tile];                                                  \
    const int off = offsets[p];                                                \
    const int cnt = offsets[p + 1] - off;

// ---------------- gemm1: R17-exact (64x128 tile, BK=64, 24KB, 6 blk/CU) ------
// Best measured 45.4us. Eight pipelining/tiling variants all lost to this
// simple 2-barrier single-buffer loop — TLP at 6 blocks/CU covers the drains.
__global__ __launch_bounds__(256, 6) void gemm1_k(
    const u16* __restrict__ xb, const u16* __restrict__ w1b,
    const float* __restrict__ b1, const int* __restrict__ perm,
    const int* __restrict__ offsets, const int* __restrict__ meta,
    const int* __restrict__ tp, const int* __restrict__ tm,
    u16* __restrict__ hb)
{
    __shared__ __align__(16) u16 smem[12288];   // sA 8KB | sB 16KB; sOut 16KB reuse
    XCD_MAP(8, 0)
    const int n0v = sub * 128;

    u16* const sA = smem;
    u16* const sB = smem + 4096;

    const int tid = threadIdx.x;
    const u16* aptr[2];
    const u16* bptr[4];
#pragma unroll
    for (int c = 0; c < 2; ++c) {
        const int slot = c * 256 + tid, row = slot >> 3, ch = slot & 7;
        const int gr = min(m0 + row, cnt - 1);
        aptr[c] = xb + (size_t)perm[off + gr] * DIN + ((ch ^ (row & 7)) * 8);
    }
#pragma unroll
    for (int c = 0; c < 4; ++c) {
        const int slot = c * 256 + tid, row = slot >> 3, ch = slot & 7;
        bptr[c] = w1b + ((size_t)p * DHID + n0v + row) * DIN + ((ch ^ (row & 7)) * 8);
    }
    const int wave = tid >> 6, lane = tid & 63;
    const int wr = wave >> 1, wc = wave & 1;    // 2x2 waves, wave tile 32x64
    const int lm = lane & 15, lk = lane >> 4;

    f32x4 acc[2][4];
#pragma unroll
    for (int a = 0; a < 2; ++a)
#pragma unroll
        for (int b = 0; b < 4; ++b) acc[a][b] = (f32x4){0.f, 0.f, 0.f, 0.f};

    for (int kt = 0; kt < DIN / 64; ++kt) {
        const int k0 = kt * 64;
#pragma unroll
        for (int c = 0; c < 2; ++c) gl_lds16(aptr[c] + k0, sA + c * 2048 + tid * 8);
#pragma unroll
        for (int c = 0; c < 4; ++c) gl_lds16(bptr[c] + k0, sB + c * 2048 + tid * 8);
        __syncthreads();
#pragma unroll
        for (int kk = 0; kk < 2; ++kk) {
            f16x8 af[2], bf[4];
#pragma unroll
            for (int mf = 0; mf < 2; ++mf) {
                const int row = wr * 32 + mf * 16 + lm;
                const int g   = kk * 4 + lk;
                af[mf] = *(const f16x8*)(sA + row * 64 + ((g ^ (row & 7)) * 8));
            }
#pragma unroll
            for (int nf = 0; nf < 4; ++nf) {
                const int row = wc * 64 + nf * 16 + lm;
                const int g   = kk * 4 + lk;
                bf[nf] = *(const f16x8*)(sB + row * 64 + ((g ^ (row & 7)) * 8));
            }
#pragma unroll
            for (int mf = 0; mf < 2; ++mf)
#pragma unroll
                for (int nf = 0; nf < 4; ++nf)
                    acc[mf][nf] = __builtin_amdgcn_mfma_f32_16x16x32_f16(
                        af[mf], bf[nf], acc[mf][nf], 0, 0, 0);
        }
        __syncthreads();
    }

    // ---- epilogue: fast gelu -> chunk-swizzled sOut, then coalesced copy-out ----
    u16* const sOut = smem;                     // 64 x 128 u16 = 16KB
#pragma unroll
    for (int nf = 0; nf < 4; ++nf) {
        const int col = wc * 64 + nf * 16 + lm;
        const float bb = b1[p * DHID + n0v + col];
        const int cc = col >> 3, c7 = col & 7;
#pragma unroll
        for (int mf = 0; mf < 2; ++mf) {
#pragma unroll
            for (int j = 0; j < 4; ++j) {
                const int tok = wr * 32 + mf * 16 + lk * 4 + j;
                sOut[tok * 128 + ((cc ^ (tok & 15)) * 8) + c7] =
                    f2h_bits(gelu_fast(acc[mf][nf][j] + bb));
            }
        }
    }
    __syncthreads();
    const int r = tid >> 2, qq = tid & 3;       // 4 threads/row, 64B each
    if (m0 + r < cnt) {
        u16* dst = hb + (size_t)(off + m0 + r) * DHID + n0v;
#pragma unroll
        for (int c = 0; c < 4; ++c) {
            const int l = qq * 4 + c;
            *(int4*)(dst + l * 8) = *(const int4*)(sOut + r * 128 + ((l ^ (r & 15)) * 8));
        }
    }
}

// ---------------- gemm2: R17-exact + REVERSED tile order (hot-tail L2 reuse) --
__global__ __launch_bounds__(256, 6) void gemm2_k(
    const u16* __restrict__ hb, const u16* __restrict__ w2b,
    const float* __restrict__ b2, const int* __restrict__ perm,
    const int* __restrict__ offsets, const int* __restrict__ meta,
    const int* __restrict__ tp, const int* __restrict__ tm,
    float* __restrict__ out)
{
    __shared__ __align__(16) u16 smem[12288];   // sA 8KB | sB 16KB
    XCD_MAP(2, 1)
    const int n0v = sub * 128;

    u16* const sA = smem;
    u16* const sB = smem + 4096;

    const int tid = threadIdx.x;
    const u16* aptr[2];
    const u16* bptr[4];
#pragma unroll
    for (int c = 0; c < 2; ++c) {
        const int slot = c * 256 + tid, row = slot >> 3, ch = slot & 7;
        aptr[c] = hb + (size_t)(off + min(m0 + row, cnt - 1)) * DHID + ((ch ^ (row & 7)) * 8);
    }
#pragma unroll
    for (int c = 0; c < 4; ++c) {
        const int slot = c * 256 + tid, row = slot >> 3, ch = slot & 7;
        bptr[c] = w2b + ((size_t)p * DOUT + n0v + row) * DHID + ((ch ^ (row & 7)) * 8);
    }
    const int wave = tid >> 6, lane = tid & 63;
    const int wr = wave >> 1, wc = wave & 1;    // 2x2 waves, wave tile 32x64
    const int lm = lane & 15, lk = lane >> 4;

    f32x4 acc[2][4];
#pragma unroll
    for (int a = 0; a < 2; ++a)
#pragma unroll
        for (int b = 0; b < 4; ++b) acc[a][b] = (f32x4){0.f, 0.f, 0.f, 0.f};

    for (int kt = 0; kt < DHID / 64; ++kt) {    // 16 K-steps
        const int k0 = kt * 64;
#pragma unroll
        for (int c = 0; c < 2; ++c) gl_lds16(aptr[c] + k0, sA + c * 2048 + tid * 8);
#pragma unroll
        for (int c = 0; c < 4; ++c) gl_lds16(bptr[c] + k0, sB + c * 2048 + tid * 8);
        __syncthreads();
#pragma unroll
        for (int kk = 0; kk < 2; ++kk) {
            f16x8 af[2], bf[4];
#pragma unroll
            for (int mf = 0; mf < 2; ++mf) {
                const int row = wr * 32 + mf * 16 + lm;
                const int g   = kk * 4 + lk;
                af[mf] = *(const f16x8*)(sA + row * 64 + ((g ^ (row & 7)) * 8));
            }
#pragma unroll
            for (int nf = 0; nf < 4; ++nf) {
                const int row = wc * 64 + nf * 16 + lm;
                const int g   = kk * 4 + lk;
                bf[nf] = *(const f16x8*)(sB + row * 64 + ((g ^ (row & 7)) * 8));
            }
#pragma unroll
            for (int mf = 0; mf < 2; ++mf)
#pragma unroll
                for (int nf = 0; nf < 4; ++nf)
                    acc[mf][nf] = __builtin_amdgcn_mfma_f32_16x16x32_f16(
                        af[mf], bf[nf], acc[mf][nf], 0, 0, 0);
        }
        __syncthreads();
    }

#pragma unroll
    for (int nf = 0; nf < 4; ++nf) {
        const int col = n0v + wc * 64 + nf * 16 + lm;
        const float bb = b2[p * DOUT + col];
#pragma unroll
        for (int mf = 0; mf < 2; ++mf) {
#pragma unroll
            for (int j = 0; j < 4; ++j) {
                const int tok = wr * 32 + mf * 16 + lk * 4 + j;
                if (m0 + tok < cnt)
                    out[(size_t)perm[off + m0 + tok] * DOUT + col] = acc[mf][nf][j] + bb;
            }
        }
    }
}

// ---------------- launch ----------------
extern "C" void kernel_launch(void* const* d_in, const int* in_sizes, int n_in,
                              void* d_out, int out_size, void* d_ws, size_t ws_size,
                              hipStream_t stream) {
    const float* x    = (const float*)d_in[0];
    const float* W1   = (const float*)d_in[1];
    const float* b1   = (const float*)d_in[2];
    const float* W2   = (const float*)d_in[3];
    const float* b2   = (const float*)d_in[4];
    const int*   pidx = (const int*)d_in[5];
    float*       out  = (float*)d_out;

    char* ws      = (char*)d_ws;
    int* offsets  = (int*)(ws + WS_OFFSETS);
    int* meta     = (int*)(ws + WS_META);
    int* tp       = (int*)(ws + WS_TP);
    int* tm       = (int*)(ws + WS_TM);
    int* blkhist  = (int*)(ws + WS_BLKHIST);
    int* perm     = (int*)(ws + WS_PERM);
    u16* xb       = (u16*)(ws + WS_XB);
    u16* w1b      = (u16*)(ws + WS_W1B);
    u16* w2b      = (u16*)(ws + WS_W2B);
    u16* hb       = (u16*)(ws + WS_HB);

    prep_k<<<2048, 256, 0, stream>>>(pidx, x, W1, W2, blkhist, xb, w1b, w2b);
    scatter_k<<<NBLK, 256, 0, stream>>>(pidx, blkhist, offsets, meta, tp, tm, perm);

    // ntiles <= 519 -> tn <= 66/xcd
    // gemm1: NSPLIT=8 (128-col chunks of DHID) -> 8*66*8 = 4224 slots
    gemm1_k<<<4224, 256, 0, stream>>>(xb, w1b, b1, perm, offsets, meta, tp, tm, hb);
    // gemm2: NSPLIT=2 (128-col chunks of DOUT) -> 8*66*2 = 1056 slots
    gemm2_k<<<1056, 256, 0, stream>>>(hb, w2b, b2, perm, offsets, meta, tp, tm, out);
}